// Round 6
// baseline (241.393 us; speedup 1.0000x reference)
//
#include <hip/hip_runtime.h>
#include <float.h>
#include <stdint.h>

// WindowRouting: out[b][q][0..3] = indices of top-4 of (Q[b,q,:] . I[b,m,:]) over m.
// Scale dropped (order-preserving).
//
// R14: FUSION. R11/R13 showed the main kernel invariant at ~70us across 2 and
// 3.2 waves/SIMD (no pipe >44%; VALUBusy+MfmaUtil ~63% both) -> wave count is
// not the lever. Meanwhile total(133.6) - GPU work(~76) = ~58us gap, stable
// across rounds = suspected inter-kernel/launch overhead of the 2-dispatch
// graph. This round: single kernel = convert phase + device-scope grid barrier
// + R11 main body VERBATIM. Barrier: sense-free epoch (cnt self-resets; flag
// monotone; 8B memsetAsync each launch is idempotent), __threadfence release/
// acquire for cross-XCD visibility. Co-residency: 256 blocks <= 256 CUs at
// >=1 block/CU (VGPR ~100) -> guaranteed.
// Decisive outcome: total ~85-95us => gap was launch overhead (win);
// total ~125-135us => fixed per-graph cost (redirect to step-loop VALU cut).
//
// Main body (proven 69.7us): 256 blocks x 512 thr, launch_bounds(512,1).
// Block = 64 q x all 8192 m. Wave = m-eighth (64 half-tiles of 16 m). 4
// q-strips of 16 (bfrag pinned, 64 VGPRs); 3-deep rotating 16-reg image ring;
// 16 MFMAs consume R before refill. Scores -> packed keys (low 11 bits =
// 2047 - m_local); running top-4 via v_max + 3x v_med3 per strip; quad-tree
// shfl merge (snapshot-first); 32 cand/row -> rank-select top-8 -> fp64
// refine -> exact top-4 (value desc, index asc).
// Fallback: fp32 LDS-tiled kernel if ws too small.

#define NBATCH 4
#define NQ 4096
#define NM 8192
#define KD 128

typedef unsigned short ushort_t;
typedef __attribute__((ext_vector_type(8))) short bf16x8;
typedef __attribute__((ext_vector_type(4))) float f32x4;

#define BETTER64(v, i, w, j) (((v) > (w)) || ((v) == (w) && (i) < (j)))

__device__ inline float fmed3(float a, float b, float c) {
#if __has_builtin(__builtin_amdgcn_fmed3f)
  return __builtin_amdgcn_fmed3f(a, b, c);
#else
  return fmaxf(fminf(a, b), fminf(fmaxf(a, b), c));
#endif
}

__device__ inline ushort_t f2bf(float f) {
  unsigned u = __float_as_uint(f);
  u += 0x7fffu + ((u >> 16) & 1u);  // RNE
  return (ushort_t)(u >> 16);
}

__device__ inline unsigned pk2(float a, float b) {
  return (unsigned)f2bf(a) | ((unsigned)f2bf(b) << 16);
}

// ---------------- Fused: convert + grid barrier + MFMA screen + refine ----------------
__global__ __launch_bounds__(512, 1) void wr_fused(
    const float* __restrict__ qry, const float* __restrict__ img,
    ushort_t* __restrict__ qb, int4* __restrict__ ib,
    int* __restrict__ bar,  // bar[0]=cnt (must be 0 at entry), bar[1]=epoch flag
    int* __restrict__ out) {
  const int bid = (int)blockIdx.x;  // 0..255
  const int tid = (int)threadIdx.x;

  // ======== Phase A: fp32 -> bf16 convert (grid-stride, exact coverage) ========
  // ib flat int4 index t (within batch): tt = tile*512 + htl*256 + ks*64 + l
  //   -> row m = tile*32 + htl*16 + (l&15), k0 = ks*32 + (l>>4)*8, 8 bf16.
#pragma unroll
  for (int i = 0; i < 4; ++i) {
    const int t = i * 131072 + bid * 512 + tid;  // 0..524287: image units
    const int b = t >> 17;
    const int tt = t & 131071;
    const int tile = tt >> 9;
    const int n = tt & 511;
    const int l = n & 63;
    const int m = tile * 32 + (n >> 8) * 16 + (l & 15);
    const int k0 = ((n >> 6) & 3) * 32 + ((l >> 4) & 3) * 8;
    const float* src = img + ((size_t)(b * NM + m)) * KD + k0;
    const float4 v0 = *(const float4*)(src);
    const float4 v1 = *(const float4*)(src + 4);
    int4 o;
    o.x = (int)pk2(v0.x, v0.y);
    o.y = (int)pk2(v0.z, v0.w);
    o.z = (int)pk2(v1.x, v1.y);
    o.w = (int)pk2(v1.z, v1.w);
    ib[t] = o;
  }
#pragma unroll
  for (int i = 0; i < 2; ++i) {
    const int u = i * 131072 + bid * 512 + tid;  // 0..262143: query units
    const float4 v0 = ((const float4*)qry)[2 * u];
    const float4 v1 = ((const float4*)qry)[2 * u + 1];
    int4 o;
    o.x = (int)pk2(v0.x, v0.y);
    o.y = (int)pk2(v0.z, v0.w);
    o.z = (int)pk2(v1.x, v1.y);
    o.w = (int)pk2(v1.z, v1.w);
    ((int4*)qb)[u] = o;
  }

  // ======== Grid barrier (device scope; replay-safe) ========
  __threadfence();   // release: write back this XCD's L2 (conversion stores)
  __syncthreads();   // whole block done + fenced
  if (tid == 0) {
    int* cnt = bar;
    int* flag = bar + 1;
    const int g = __hip_atomic_load(flag, __ATOMIC_ACQUIRE, __HIP_MEMORY_SCOPE_AGENT);
    const int old =
        __hip_atomic_fetch_add(cnt, 1, __ATOMIC_ACQ_REL, __HIP_MEMORY_SCOPE_AGENT);
    if (old == (int)gridDim.x - 1) {
      // last arriver: reset cnt for next replay, then release the barrier
      __hip_atomic_store(cnt, 0, __ATOMIC_RELAXED, __HIP_MEMORY_SCOPE_AGENT);
      __hip_atomic_store(flag, g + 1, __ATOMIC_RELEASE, __HIP_MEMORY_SCOPE_AGENT);
    } else {
      while (__hip_atomic_load(flag, __ATOMIC_ACQUIRE, __HIP_MEMORY_SCOPE_AGENT) == g) {
        __builtin_amdgcn_s_sleep(1);
      }
    }
  }
  __syncthreads();
  __threadfence();   // acquire: invalidate L1/L2 so all ib/qb reads are fresh

  // ======== Phase B: MFMA screen + fp64 refine (R11 verbatim) ========
  const int b = (bid & 7) >> 1;                  // batch pinned to XCD pair
  const int qt = ((bid >> 3) << 1) | (bid & 1);  // 0..63
  const int qbase = qt * 64;

  const int lane = tid & 63;
  const int w = tid >> 6;        // 0..7 -> m-eighth (64 half-tiles of 16 m)
  const int q15 = lane & 15;
  const int quad = lane >> 4;    // 0..3

  const ushort_t* Qb = qb + ((size_t)b * NQ + qbase) * KD;
  const int4* ibc = ib + (size_t)b * 131072;

  // query fragments pinned: 4 strips of 16 q. B[n=q15][k = ks*32 + quad*8 + j]
  bf16x8 bfrag[4][4];  // [strip][ks] -> 64 VGPRs
#pragma unroll
  for (int s = 0; s < 4; ++s)
#pragma unroll
    for (int ks = 0; ks < 4; ++ks)
      bfrag[s][ks] =
          *(const bf16x8*)(Qb + (size_t)(s * 16 + q15) * KD + ks * 32 + quad * 8);

  float tch[4][4];  // one packed-key top-4 chain per strip
#pragma unroll
  for (int s = 0; s < 4; ++s)
#pragma unroll
    for (int e = 0; e < 4; ++e) tch[s][e] = -FLT_MAX;

  bf16x8 B0[4], B1[4], B2[4];  // 3-deep ring, 16 regs each

  auto loadH = [&](bf16x8* R, int h) {
    const int4* p = ibc + (((w * 64 + h) << 8) + lane);
#pragma unroll
    for (int ks = 0; ks < 4; ++ks) R[ks] = *(const bf16x8*)(p + ks * 64);
  };

  int hl = 3;
  int vb = 2047 - 4 * quad;  // key base; m_local = 16*h + 4*quad + r  (< 1024)

  auto step = [&](bf16x8* R) {
    f32x4 a[4];
#pragma unroll
    for (int s = 0; s < 4; ++s) a[s] = {0.f, 0.f, 0.f, 0.f};
    // all 16 MFMAs consume R before the refill below (ring-reuse hazard)
#pragma unroll
    for (int ks = 0; ks < 4; ++ks)
#pragma unroll
      for (int s = 0; s < 4; ++s)
        a[s] = __builtin_amdgcn_mfma_f32_16x16x32_bf16(R[ks], bfrag[s][ks], a[s],
                                                       0, 0, 0);
    if (hl < 64) loadH(R, hl);  // refill for use 3 steps later
    ++hl;
#pragma unroll
    for (int s = 0; s < 4; ++s) {
#pragma unroll
      for (int r = 0; r < 4; ++r) {
        const unsigned kr = (unsigned)(vb - r);
        const float k =
            __uint_as_float((__float_as_uint(a[s][r]) & 0xFFFFF800u) | kr);
        tch[s][3] = fmed3(k, tch[s][2], tch[s][3]);
        tch[s][2] = fmed3(k, tch[s][1], tch[s][2]);
        tch[s][1] = fmed3(k, tch[s][0], tch[s][1]);
        tch[s][0] = fmaxf(tch[s][0], k);
      }
    }
    vb -= 16;
  };

  loadH(B0, 0);
  loadH(B1, 1);
  loadH(B2, 2);
  for (int g = 0; g < 21; ++g) { step(B0); step(B1); step(B2); }
  step(B0);  // half-tile 63

  // ---- quad-tree merge per strip (snapshot donor regs BEFORE mutating) ----
#pragma unroll
  for (int s = 0; s < 4; ++s) {
    float k4[4];
#pragma unroll
    for (int e = 0; e < 4; ++e) k4[e] = __shfl_down(tch[s][e], 32, 64);
#pragma unroll
    for (int e = 0; e < 4; ++e) {
      const float k = k4[e];
      tch[s][3] = fmed3(k, tch[s][2], tch[s][3]);
      tch[s][2] = fmed3(k, tch[s][1], tch[s][2]);
      tch[s][1] = fmed3(k, tch[s][0], tch[s][1]);
      tch[s][0] = fmaxf(tch[s][0], k);
    }
#pragma unroll
    for (int e = 0; e < 4; ++e) k4[e] = __shfl_down(tch[s][e], 16, 64);
#pragma unroll
    for (int e = 0; e < 4; ++e) {
      const float k = k4[e];
      tch[s][3] = fmed3(k, tch[s][2], tch[s][3]);
      tch[s][2] = fmed3(k, tch[s][1], tch[s][2]);
      tch[s][1] = fmed3(k, tch[s][0], tch[s][1]);
      tch[s][0] = fmaxf(tch[s][0], k);
    }
  }

  // ---- 32 candidates per q-row (8 eighths x 4), 64 rows ----
  __shared__ float ck[64][33];
  __shared__ int top8[64][8];
  __shared__ double pd[64][8];
  __shared__ int pi[64][8];

  if (lane < 16) {
#pragma unroll
    for (int s = 0; s < 4; ++s)
#pragma unroll
      for (int e = 0; e < 4; ++e) ck[s * 16 + q15][w * 4 + e] = tch[s][e];
  }
  __syncthreads();

  // ---- rank-select top-8 of 32 packed keys per row (ranks unique) ----
  for (int p = tid; p < 2048; p += 512) {
    const int q = p >> 5;
    const int j = p & 31;
    const float k = ck[q][j];
    int rank = 0;
#pragma unroll 8
    for (int i = 0; i < 32; ++i) {
      const float o = ck[q][i];
      rank += (o > k) || (o == k && i < j);
    }
    if (rank < 8) {
      const unsigned bits = __float_as_uint(k);
      top8[q][rank] = (j >> 2) * 1024 + 2047 - (int)(bits & 0x7FFu);
    }
  }
  __syncthreads();

  // ---- fp64 refine: one candidate per thread (64 rows x 8) ----
  {
    const int q = tid >> 3;
    const int slot = tid & 7;
    const int m = top8[q][slot];
    const float* qrow = qry + ((size_t)b * NQ + qbase + q) * KD;
    const float* irow = img + ((size_t)b * NM + m) * KD;
    double s0 = 0.0, s1 = 0.0, s2 = 0.0, s3 = 0.0;
#pragma unroll
    for (int k = 0; k < KD; k += 4) {
      const float4 xv = *(const float4*)(qrow + k);
      const float4 yv = *(const float4*)(irow + k);
      s0 = fma((double)xv.x, (double)yv.x, s0);
      s1 = fma((double)xv.y, (double)yv.y, s1);
      s2 = fma((double)xv.z, (double)yv.z, s2);
      s3 = fma((double)xv.w, (double)yv.w, s3);
    }
    pd[q][slot] = (s0 + s1) + (s2 + s3);
    pi[q][slot] = m;
  }
  __syncthreads();

  // ---- exact top-4 of 8 refined, (value desc, index asc) ----
  if (tid < 64) {
    const int q = tid;
    double fv[4];
    int fi[4];
#pragma unroll
    for (int e = 0; e < 4; ++e) { fv[e] = -DBL_MAX; fi[e] = 0x7fffffff; }
    for (int sl = 0; sl < 8; ++sl) {
      const double v = pd[q][sl];
      const int m = pi[q][sl];
      const bool b0 = BETTER64(v, m, fv[0], fi[0]);
      const bool b1 = BETTER64(v, m, fv[1], fi[1]);
      const bool b2 = BETTER64(v, m, fv[2], fi[2]);
      const bool b3 = BETTER64(v, m, fv[3], fi[3]);
      fv[3] = b2 ? fv[2] : (b3 ? v : fv[3]);
      fi[3] = b2 ? fi[2] : (b3 ? m : fi[3]);
      fv[2] = b1 ? fv[1] : (b2 ? v : fv[2]);
      fi[2] = b1 ? fi[1] : (b2 ? m : fi[2]);
      fv[1] = b0 ? fv[0] : (b1 ? v : fv[1]);
      fi[1] = b0 ? fi[0] : (b1 ? m : fi[1]);
      fv[0] = b0 ? v : fv[0];
      fi[0] = b0 ? m : fi[0];
    }
    int4 o;
    o.x = fi[0]; o.y = fi[1]; o.z = fi[2]; o.w = fi[3];
    *(int4*)(out + ((size_t)b * NQ + qbase + q) * 4) = o;
  }
}

// ---------------- Fallback: fp32 LDS-tiled kernel (ws too small) ----------------
#define QT 64
#define MT 128
#define KC 64
#define NTHREADS 512

__global__ __launch_bounds__(NTHREADS) void wr_main(const float* __restrict__ qry,
                                                    const float* __restrict__ img,
                                                    int* __restrict__ out) {
  __shared__ __align__(16) float A_lds[KD * QT];
  __shared__ __align__(16) float B_lds[KC * MT];

  const int t = (int)threadIdx.x;
  const int b = (int)blockIdx.x >> 6;
  const int qbase = ((int)blockIdx.x & 63) * QT;

  const float* qp = qry + ((size_t)b * NQ + qbase) * KD;
  const float* ip = img + (size_t)b * NM * KD;

  {
    const int r = t >> 3;
    const int kc = t & 7;
    const float* src = qp + (size_t)r * KD;
#pragma unroll
    for (int i = 0; i < 4; ++i) {
      const int k0 = kc * 4 + i * 32;
      const float4 v = *(const float4*)(src + k0);
      A_lds[(k0 + 0) * QT + r] = v.x;
      A_lds[(k0 + 1) * QT + r] = v.y;
      A_lds[(k0 + 2) * QT + r] = v.z;
      A_lds[(k0 + 3) * QT + r] = v.w;
    }
  }

  const int qi = t >> 5;
  const int mi = t & 31;

  float tv[4][4];
  int ti[4][4];
#pragma unroll
  for (int j = 0; j < 4; ++j)
#pragma unroll
    for (int s = 0; s < 4; ++s) { tv[j][s] = -FLT_MAX; ti[j][s] = 0x7fffffff; }

  for (int tile = 0; tile < NM / MT; ++tile) {
    const int mbase = tile * MT;
    float acc[4][4];
#pragma unroll
    for (int j = 0; j < 4; ++j)
#pragma unroll
      for (int s = 0; s < 4; ++s) acc[j][s] = 0.0f;

    for (int kb = 0; kb < KD; kb += KC) {
      __syncthreads();
      {
        const int r = t >> 2;
        const int kc = t & 3;
        const float* src = ip + (size_t)(mbase + r) * KD + kb;
#pragma unroll
        for (int i = 0; i < 4; ++i) {
          const int k0 = kc * 4 + i * 16;
          const float4 v = *(const float4*)(src + k0);
          B_lds[(k0 + 0) * MT + r] = v.x;
          B_lds[(k0 + 1) * MT + r] = v.y;
          B_lds[(k0 + 2) * MT + r] = v.z;
          B_lds[(k0 + 3) * MT + r] = v.w;
        }
      }
      __syncthreads();

#pragma unroll 8
      for (int k = 0; k < KC; ++k) {
        const float4 av = *(const float4*)&A_lds[(kb + k) * QT + qi * 4];
        const float4 bv = *(const float4*)&B_lds[k * MT + mi * 4];
        acc[0][0] = fmaf(av.x, bv.x, acc[0][0]);
        acc[0][1] = fmaf(av.x, bv.y, acc[0][1]);
        acc[0][2] = fmaf(av.x, bv.z, acc[0][2]);
        acc[0][3] = fmaf(av.x, bv.w, acc[0][3]);
        acc[1][0] = fmaf(av.y, bv.x, acc[1][0]);
        acc[1][1] = fmaf(av.y, bv.y, acc[1][1]);
        acc[1][2] = fmaf(av.y, bv.z, acc[1][2]);
        acc[1][3] = fmaf(av.y, bv.w, acc[1][3]);
        acc[2][0] = fmaf(av.z, bv.x, acc[2][0]);
        acc[2][1] = fmaf(av.z, bv.y, acc[2][1]);
        acc[2][2] = fmaf(av.z, bv.z, acc[2][2]);
        acc[2][3] = fmaf(av.z, bv.w, acc[2][3]);
        acc[3][0] = fmaf(av.w, bv.x, acc[3][0]);
        acc[3][1] = fmaf(av.w, bv.y, acc[3][1]);
        acc[3][2] = fmaf(av.w, bv.z, acc[3][2]);
        acc[3][3] = fmaf(av.w, bv.w, acc[3][3]);
      }
    }

#pragma unroll
    for (int j = 0; j < 4; ++j) {
#pragma unroll
      for (int s = 0; s < 4; ++s) {
        const float v = acc[j][s];
        const int m = mbase + mi * 4 + s;
        const bool b0 = v > tv[j][0];
        const bool b1 = v > tv[j][1];
        const bool b2 = v > tv[j][2];
        const bool b3 = v > tv[j][3];
        tv[j][3] = b2 ? tv[j][2] : (b3 ? v : tv[j][3]);
        ti[j][3] = b2 ? ti[j][2] : (b3 ? m : ti[j][3]);
        tv[j][2] = b1 ? tv[j][1] : (b2 ? v : tv[j][2]);
        ti[j][2] = b1 ? ti[j][1] : (b2 ? m : ti[j][2]);
        tv[j][1] = b0 ? tv[j][0] : (b1 ? v : tv[j][1]);
        ti[j][1] = b0 ? ti[j][0] : (b1 ? m : ti[j][1]);
        tv[j][0] = b0 ? v : tv[j][0];
        ti[j][0] = b0 ? m : ti[j][0];
      }
    }
  }

  __syncthreads();
  int* idx_lds = (int*)B_lds;
#pragma unroll
  for (int j = 0; j < 4; ++j)
#pragma unroll
    for (int s = 0; s < 4; ++s)
      idx_lds[(qi * 4 + j) * 128 + mi * 4 + s] = ti[j][s];
  __syncthreads();

  double* pv = (double*)A_lds;
  int* piL = (int*)(A_lds + 4096);
  {
    const int r = t >> 3;
    const int slot = t & 7;
    const float* qrow = qp + (size_t)r * KD;
    double bv[4];
    int bi[4];
#pragma unroll
    for (int e = 0; e < 4; ++e) { bv[e] = -DBL_MAX; bi[e] = 0x7fffffff; }

    for (int c = 0; c < 16; ++c) {
      const int m = idx_lds[r * 128 + slot * 16 + c];
      const float* irow = ip + (size_t)m * KD;
      double s0 = 0.0, s1 = 0.0, s2 = 0.0, s3 = 0.0;
#pragma unroll
      for (int k = 0; k < KD; k += 4) {
        const float4 xv = *(const float4*)(qrow + k);
        const float4 yv = *(const float4*)(irow + k);
        s0 = fma((double)xv.x, (double)yv.x, s0);
        s1 = fma((double)xv.y, (double)yv.y, s1);
        s2 = fma((double)xv.z, (double)yv.z, s2);
        s3 = fma((double)xv.w, (double)yv.w, s3);
      }
      const double v = (s0 + s1) + (s2 + s3);
      const bool b0 = BETTER64(v, m, bv[0], bi[0]);
      const bool b1 = BETTER64(v, m, bv[1], bi[1]);
      const bool b2 = BETTER64(v, m, bv[2], bi[2]);
      const bool b3 = BETTER64(v, m, bv[3], bi[3]);
      bv[3] = b2 ? bv[2] : (b3 ? v : bv[3]);
      bi[3] = b2 ? bi[2] : (b3 ? m : bi[3]);
      bv[2] = b1 ? bv[1] : (b2 ? v : bv[2]);
      bi[2] = b1 ? bi[1] : (b2 ? m : bi[2]);
      bv[1] = b0 ? bv[0] : (b1 ? v : bv[1]);
      bi[1] = b0 ? bi[0] : (b1 ? m : bi[1]);
      bv[0] = b0 ? v : bv[0];
      bi[0] = b0 ? m : bi[0];
    }
#pragma unroll
    for (int e = 0; e < 4; ++e) {
      pv[t * 4 + e] = bv[e];
      piL[t * 4 + e] = bi[e];
    }
  }
  __syncthreads();

  if (t < QT) {
    double fv[4];
    int fi[4];
#pragma unroll
    for (int e = 0; e < 4; ++e) { fv[e] = -DBL_MAX; fi[e] = 0x7fffffff; }
    for (int sl = 0; sl < 8; ++sl) {
#pragma unroll
      for (int e = 0; e < 4; ++e) {
        const double v = pv[(t * 8 + sl) * 4 + e];
        const int m = piL[(t * 8 + sl) * 4 + e];
        const bool b0 = BETTER64(v, m, fv[0], fi[0]);
        const bool b1 = BETTER64(v, m, fv[1], fi[1]);
        const bool b2 = BETTER64(v, m, fv[2], fi[2]);
        const bool b3 = BETTER64(v, m, fv[3], fi[3]);
        fv[3] = b2 ? fv[2] : (b3 ? v : fv[3]);
        fi[3] = b2 ? fi[2] : (b3 ? m : fi[3]);
        fv[2] = b1 ? fv[1] : (b2 ? v : fv[2]);
        fi[2] = b1 ? fi[1] : (b2 ? m : fi[2]);
        fv[1] = b0 ? fv[0] : (b1 ? v : fv[1]);
        fi[1] = b0 ? fi[0] : (b1 ? m : fi[1]);
        fv[0] = b0 ? v : fv[0];
        fi[0] = b0 ? m : fi[0];
      }
    }
    int4 o;
    o.x = fi[0]; o.y = fi[1]; o.z = fi[2]; o.w = fi[3];
    *(int4*)(out + ((size_t)b * NQ + qbase + t) * 4) = o;
  }
}

extern "C" void kernel_launch(void* const* d_in, const int* in_sizes, int n_in,
                              void* d_out, int out_size, void* d_ws, size_t ws_size,
                              hipStream_t stream) {
  const float* qry = (const float*)d_in[0];  // (4, 4096, 128) fp32
  const float* img = (const float*)d_in[1];  // (4, 8192, 128) fp32
  int* out = (int*)d_out;                    // (4, 4096, 4) int32

  const size_t qbBytes = (size_t)NBATCH * NQ * KD * sizeof(ushort_t);  // 4 MB
  const size_t ibBytes = (size_t)NBATCH * NM * KD * sizeof(ushort_t);  // 8 MB

  if (ws_size >= qbBytes + ibBytes + 64) {
    ushort_t* qb = (ushort_t*)d_ws;
    int4* ib = (int4*)((char*)d_ws + qbBytes);
    int* bar = (int*)((char*)d_ws + qbBytes + ibBytes);
    // idempotent per-launch reset of {cnt, flag}; graph-capturable stream op
    hipMemsetAsync(bar, 0, 2 * sizeof(int), stream);
    wr_fused<<<256, 512, 0, stream>>>(qry, img, qb, ib, bar, out);
  } else {
    wr_main<<<NBATCH * (NQ / QT), NTHREADS, 0, stream>>>(qry, img, out);
  }
}

// Round 7
// 160.435 us; speedup vs baseline: 1.5046x; 1.5046x over previous
//
#include <hip/hip_runtime.h>
#include <float.h>
#include <stdint.h>

// WindowRouting: out[b][q][0..3] = indices of top-4 of (Q[b,q,:] . I[b,m,:]) over m.
// Scale dropped (order-preserving).
//
// R15 = R11 two-kernel structure + group-max screening with a SAFE epilogue.
// Ledger (R14): total-minus-kernel gap ~57us is fixed per-graph overhead
// (identical for 1 and 2 dispatches) -> only kernel time matters. wr_mfma
// issue audit: ~350 cy/step issued vs 1312 cy/step-slot; selection VALU is
// 2x MFMA issue. This round cuts selection ~3x:
//   (a) group-of-4 max screen (R9-validated, absmax 0.0): per strip per step
//       insert ONE key = max of lane's 4 consecutive m; low 11 bits =
//       2047 - gid, gid = 4h+quad < 256. Guarantee: group holding rank-k elem
//       is within top-k groups by group-max (k<=4 = chain depth).
//   (b) hoisted z4 C-operand on first MFMA (no per-step zero-init).
//   (c) SAFE epilogue (R9/R10 bug was LICM over shared qrow in unrolled jj
//       loop -> 128 VGPR hoist -> 176MB scratch): refine 32 cands/row as 4x
//       '#pragma unroll 1' iterations, one cand/thread, q VARIES per iteration
//       (q = k*16 + tid>>5) so nothing is invariant; body = R8's VGPR-100 code.
// Sentinels: VGPR <= ~110, WRITE_SIZE <= ~1MB, FETCH <= ~45MB.
//
// K0 (wr_cvt): fp32 -> bf16, DIRECT (no LDS/sync).
// K1 (wr_mfma): 256 blocks x 512 thr, launch_bounds(512,1). Block = 64 q x all
//   8192 m; wave = m-eighth (64 half-tiles of 16 m); 4 q-strips of 16 (bfrag
//   pinned, 64 VGPRs); 3-deep rotating 16-reg image ring; 16 MFMAs consume R
//   before refill. Quad-tree shfl merge (snapshot-first); 32 group keys/row ->
//   rank-select top-8 groups -> fp64 refine 32 cands -> exact top-4.
// Fallback: fp32 LDS-tiled kernel if ws too small.

#define NBATCH 4
#define NQ 4096
#define NM 8192
#define KD 128

typedef unsigned short ushort_t;
typedef __attribute__((ext_vector_type(8))) short bf16x8;
typedef __attribute__((ext_vector_type(4))) float f32x4;

#define BETTER64(v, i, w, j) (((v) > (w)) || ((v) == (w) && (i) < (j)))

__device__ inline float fmed3(float a, float b, float c) {
#if __has_builtin(__builtin_amdgcn_fmed3f)
  return __builtin_amdgcn_fmed3f(a, b, c);
#else
  return fmaxf(fminf(a, b), fminf(fmaxf(a, b), c));
#endif
}

__device__ inline ushort_t f2bf(float f) {
  unsigned u = __float_as_uint(f);
  u += 0x7fffu + ((u >> 16) & 1u);  // RNE
  return (ushort_t)(u >> 16);
}

__device__ inline unsigned pk2(float a, float b) {
  return (unsigned)f2bf(a) | ((unsigned)f2bf(b) << 16);
}

// ---------------- K0: direct convert + swizzle (no LDS) ----------------
// ib flat int4 index t (within batch): tt = tile*512 + htl*256 + ks*64 + l
//   -> row m = tile*32 + htl*16 + (l&15), k0 = ks*32 + (l>>4)*8, 8 bf16 elems.
__global__ __launch_bounds__(256) void wr_cvt(const float* __restrict__ qry,
                                              const float* __restrict__ img,
                                              ushort_t* __restrict__ qb,
                                              int4* __restrict__ ib) {
  const int t = (int)blockIdx.x * 256 + (int)threadIdx.x;  // 0..786431
  if (t < 524288) {
    // image: one ib int4 per thread
    const int b = t >> 17;
    const int tt = t & 131071;
    const int tile = tt >> 9;
    const int n = tt & 511;
    const int l = n & 63;
    const int m = tile * 32 + (n >> 8) * 16 + (l & 15);
    const int k0 = ((n >> 6) & 3) * 32 + ((l >> 4) & 3) * 8;
    const float* src = img + ((size_t)(b * NM + m)) * KD + k0;
    const float4 v0 = *(const float4*)(src);
    const float4 v1 = *(const float4*)(src + 4);
    int4 o;
    o.x = (int)pk2(v0.x, v0.y);
    o.y = (int)pk2(v0.z, v0.w);
    o.z = (int)pk2(v1.x, v1.y);
    o.w = (int)pk2(v1.z, v1.w);
    ib[t] = o;
  } else {
    // query: 8 elements per thread, linear
    const int u = t - 524288;  // 0..262143
    const float4 v0 = ((const float4*)qry)[2 * u];
    const float4 v1 = ((const float4*)qry)[2 * u + 1];
    int4 o;
    o.x = (int)pk2(v0.x, v0.y);
    o.y = (int)pk2(v0.z, v0.w);
    o.z = (int)pk2(v1.x, v1.y);
    o.w = (int)pk2(v1.z, v1.w);
    ((int4*)qb)[u] = o;
  }
}

// ---------------- K1: MFMA group-max screen + fp64 refine ----------------
__global__ __launch_bounds__(512, 1) void wr_mfma(const float* __restrict__ qry,
                                                  const float* __restrict__ img,
                                                  const ushort_t* __restrict__ qb,
                                                  const int4* __restrict__ ib,
                                                  int* __restrict__ out) {
  const int bid = (int)blockIdx.x;               // 0..255
  const int b = (bid & 7) >> 1;                  // batch pinned to XCD pair
  const int qt = ((bid >> 3) << 1) | (bid & 1);  // 0..63
  const int qbase = qt * 64;

  const int tid = (int)threadIdx.x;
  const int lane = tid & 63;
  const int w = tid >> 6;        // 0..7 -> m-eighth (64 half-tiles of 16 m)
  const int q15 = lane & 15;
  const int quad = lane >> 4;    // 0..3

  const ushort_t* Qb = qb + ((size_t)b * NQ + qbase) * KD;
  const int4* ibc = ib + (size_t)b * 131072;

  // query fragments pinned: 4 strips of 16 q. B[n=q15][k = ks*32 + quad*8 + j]
  bf16x8 bfrag[4][4];  // [strip][ks] -> 64 VGPRs
#pragma unroll
  for (int s = 0; s < 4; ++s)
#pragma unroll
    for (int ks = 0; ks < 4; ++ks)
      bfrag[s][ks] =
          *(const bf16x8*)(Qb + (size_t)(s * 16 + q15) * KD + ks * 32 + quad * 8);

  float tch[4][4];  // one packed GROUP-key top-4 chain per strip
#pragma unroll
  for (int s = 0; s < 4; ++s)
#pragma unroll
    for (int e = 0; e < 4; ++e) tch[s][e] = -FLT_MAX;

  bf16x8 B0[4], B1[4], B2[4];  // 3-deep ring, 16 regs each

  auto loadH = [&](bf16x8* R, int h) {
    const int4* p = ibc + (((w * 64 + h) << 8) + lane);
#pragma unroll
    for (int ks = 0; ks < 4; ++ks) R[ks] = *(const bf16x8*)(p + ks * 64);
  };

  const f32x4 z4 = {0.f, 0.f, 0.f, 0.f};  // hoisted zero C-operand

  int hl = 3;
  int gb = 2047 - quad;  // group key base; gid = 4h + quad (< 256)

  auto step = [&](bf16x8* R) {
    f32x4 a[4];
    // all 16 MFMAs consume R before the refill below (ring-reuse hazard)
#pragma unroll
    for (int s = 0; s < 4; ++s)
      a[s] = __builtin_amdgcn_mfma_f32_16x16x32_bf16(R[0], bfrag[s][0], z4,
                                                     0, 0, 0);
#pragma unroll
    for (int ks = 1; ks < 4; ++ks)
#pragma unroll
      for (int s = 0; s < 4; ++s)
        a[s] = __builtin_amdgcn_mfma_f32_16x16x32_bf16(R[ks], bfrag[s][ks],
                                                       a[s], 0, 0, 0);
    if (hl < 64) loadH(R, hl);  // refill for use 3 steps later
    ++hl;
#pragma unroll
    for (int s = 0; s < 4; ++s) {
      const float gm =
          fmaxf(fmaxf(a[s][0], a[s][1]), fmaxf(a[s][2], a[s][3]));
      const float k =
          __uint_as_float((__float_as_uint(gm) & 0xFFFFF800u) | (unsigned)gb);
      tch[s][3] = fmed3(k, tch[s][2], tch[s][3]);
      tch[s][2] = fmed3(k, tch[s][1], tch[s][2]);
      tch[s][1] = fmed3(k, tch[s][0], tch[s][1]);
      tch[s][0] = fmaxf(tch[s][0], k);
    }
    gb -= 4;
  };

  loadH(B0, 0);
  loadH(B1, 1);
  loadH(B2, 2);
  for (int g = 0; g < 21; ++g) { step(B0); step(B1); step(B2); }
  step(B0);  // half-tile 63

  // ---- quad-tree merge per strip (snapshot donor regs BEFORE mutating) ----
#pragma unroll
  for (int s = 0; s < 4; ++s) {
    float k4[4];
#pragma unroll
    for (int e = 0; e < 4; ++e) k4[e] = __shfl_down(tch[s][e], 32, 64);
#pragma unroll
    for (int e = 0; e < 4; ++e) {
      const float k = k4[e];
      tch[s][3] = fmed3(k, tch[s][2], tch[s][3]);
      tch[s][2] = fmed3(k, tch[s][1], tch[s][2]);
      tch[s][1] = fmed3(k, tch[s][0], tch[s][1]);
      tch[s][0] = fmaxf(tch[s][0], k);
    }
#pragma unroll
    for (int e = 0; e < 4; ++e) k4[e] = __shfl_down(tch[s][e], 16, 64);
#pragma unroll
    for (int e = 0; e < 4; ++e) {
      const float k = k4[e];
      tch[s][3] = fmed3(k, tch[s][2], tch[s][3]);
      tch[s][2] = fmed3(k, tch[s][1], tch[s][2]);
      tch[s][1] = fmed3(k, tch[s][0], tch[s][1]);
      tch[s][0] = fmaxf(tch[s][0], k);
    }
  }

  // ---- 32 candidate GROUPS per q-row (8 eighths x 4), 64 rows ----
  __shared__ float ck[64][33];
  __shared__ int top8[64][8];    // group base m (batch-local)
  __shared__ double pd[64][32];  // 32 refined values per row
  __shared__ int pi[64][32];

  if (lane < 16) {
#pragma unroll
    for (int s = 0; s < 4; ++s)
#pragma unroll
      for (int e = 0; e < 4; ++e) ck[s * 16 + q15][w * 4 + e] = tch[s][e];
  }
  __syncthreads();

  // ---- rank-select top-8 of 32 packed group keys per row (ranks unique) ----
  for (int p = tid; p < 2048; p += 512) {
    const int q = p >> 5;
    const int j = p & 31;
    const float k = ck[q][j];
    int rank = 0;
#pragma unroll 8
    for (int i = 0; i < 32; ++i) {
      const float o = ck[q][i];
      rank += (o > k) || (o == k && i < j);
    }
    if (rank < 8) {
      const unsigned bits = __float_as_uint(k);
      // gid = 2047 - low11; m_base = eighth*1024 + gid*4
      top8[q][rank] = (j >> 2) * 1024 + (2047 - (int)(bits & 0x7FFu)) * 4;
    }
  }
  __syncthreads();

  // ---- fp64 refine: 32 cands/row, one cand per thread per iteration.
  // q varies per iteration (q = k4*16 + tid>>5): nothing loop-invariant,
  // unroll disabled -> no LICM register blowup (R9/R10 lesson).
#pragma unroll 1
  for (int k4 = 0; k4 < 4; ++k4) {
    const int c = k4 * 512 + tid;  // 0..2047
    const int q = c >> 5;
    const int sl = c & 31;
    const int m = top8[q][sl >> 2] + (sl & 3);
    const float* qrow = qry + ((size_t)b * NQ + qbase + q) * KD;
    const float* irow = img + ((size_t)b * NM + m) * KD;
    double s0 = 0.0, s1 = 0.0, s2 = 0.0, s3 = 0.0;
#pragma unroll
    for (int k = 0; k < KD; k += 4) {
      const float4 xv = *(const float4*)(qrow + k);
      const float4 yv = *(const float4*)(irow + k);
      s0 = fma((double)xv.x, (double)yv.x, s0);
      s1 = fma((double)xv.y, (double)yv.y, s1);
      s2 = fma((double)xv.z, (double)yv.z, s2);
      s3 = fma((double)xv.w, (double)yv.w, s3);
    }
    pd[q][sl] = (s0 + s1) + (s2 + s3);
    pi[q][sl] = m;
  }
  __syncthreads();

  // ---- exact top-4 of 32 refined, (value desc, index asc) ----
  if (tid < 64) {
    const int q = tid;
    double fv[4];
    int fi[4];
#pragma unroll
    for (int e = 0; e < 4; ++e) { fv[e] = -DBL_MAX; fi[e] = 0x7fffffff; }
    for (int sl = 0; sl < 32; ++sl) {
      const double v = pd[q][sl];
      const int m = pi[q][sl];
      const bool b0 = BETTER64(v, m, fv[0], fi[0]);
      const bool b1 = BETTER64(v, m, fv[1], fi[1]);
      const bool b2 = BETTER64(v, m, fv[2], fi[2]);
      const bool b3 = BETTER64(v, m, fv[3], fi[3]);
      fv[3] = b2 ? fv[2] : (b3 ? v : fv[3]);
      fi[3] = b2 ? fi[2] : (b3 ? m : fi[3]);
      fv[2] = b1 ? fv[1] : (b2 ? v : fv[2]);
      fi[2] = b1 ? fi[1] : (b2 ? m : fi[2]);
      fv[1] = b0 ? fv[0] : (b1 ? v : fv[1]);
      fi[1] = b0 ? fi[0] : (b1 ? m : fi[1]);
      fv[0] = b0 ? v : fv[0];
      fi[0] = b0 ? m : fi[0];
    }
    int4 o;
    o.x = fi[0]; o.y = fi[1]; o.z = fi[2]; o.w = fi[3];
    *(int4*)(out + ((size_t)b * NQ + qbase + q) * 4) = o;
  }
}

// ---------------- Fallback: fp32 LDS-tiled kernel (ws too small) ----------------
#define QT 64
#define MT 128
#define KC 64
#define NTHREADS 512

__global__ __launch_bounds__(NTHREADS) void wr_main(const float* __restrict__ qry,
                                                    const float* __restrict__ img,
                                                    int* __restrict__ out) {
  __shared__ __align__(16) float A_lds[KD * QT];
  __shared__ __align__(16) float B_lds[KC * MT];

  const int t = (int)threadIdx.x;
  const int b = (int)blockIdx.x >> 6;
  const int qbase = ((int)blockIdx.x & 63) * QT;

  const float* qp = qry + ((size_t)b * NQ + qbase) * KD;
  const float* ip = img + (size_t)b * NM * KD;

  {
    const int r = t >> 3;
    const int kc = t & 7;
    const float* src = qp + (size_t)r * KD;
#pragma unroll
    for (int i = 0; i < 4; ++i) {
      const int k0 = kc * 4 + i * 32;
      const float4 v = *(const float4*)(src + k0);
      A_lds[(k0 + 0) * QT + r] = v.x;
      A_lds[(k0 + 1) * QT + r] = v.y;
      A_lds[(k0 + 2) * QT + r] = v.z;
      A_lds[(k0 + 3) * QT + r] = v.w;
    }
  }

  const int qi = t >> 5;
  const int mi = t & 31;

  float tv[4][4];
  int ti[4][4];
#pragma unroll
  for (int j = 0; j < 4; ++j)
#pragma unroll
    for (int s = 0; s < 4; ++s) { tv[j][s] = -FLT_MAX; ti[j][s] = 0x7fffffff; }

  for (int tile = 0; tile < NM / MT; ++tile) {
    const int mbase = tile * MT;
    float acc[4][4];
#pragma unroll
    for (int j = 0; j < 4; ++j)
#pragma unroll
      for (int s = 0; s < 4; ++s) acc[j][s] = 0.0f;

    for (int kb = 0; kb < KD; kb += KC) {
      __syncthreads();
      {
        const int r = t >> 2;
        const int kc = t & 3;
        const float* src = ip + (size_t)(mbase + r) * KD + kb;
#pragma unroll
        for (int i = 0; i < 4; ++i) {
          const int k0 = kc * 4 + i * 16;
          const float4 v = *(const float4*)(src + k0);
          B_lds[(k0 + 0) * MT + r] = v.x;
          B_lds[(k0 + 1) * MT + r] = v.y;
          B_lds[(k0 + 2) * MT + r] = v.z;
          B_lds[(k0 + 3) * MT + r] = v.w;
        }
      }
      __syncthreads();

#pragma unroll 8
      for (int k = 0; k < KC; ++k) {
        const float4 av = *(const float4*)&A_lds[(kb + k) * QT + qi * 4];
        const float4 bv = *(const float4*)&B_lds[k * MT + mi * 4];
        acc[0][0] = fmaf(av.x, bv.x, acc[0][0]);
        acc[0][1] = fmaf(av.x, bv.y, acc[0][1]);
        acc[0][2] = fmaf(av.x, bv.z, acc[0][2]);
        acc[0][3] = fmaf(av.x, bv.w, acc[0][3]);
        acc[1][0] = fmaf(av.y, bv.x, acc[1][0]);
        acc[1][1] = fmaf(av.y, bv.y, acc[1][1]);
        acc[1][2] = fmaf(av.y, bv.z, acc[1][2]);
        acc[1][3] = fmaf(av.y, bv.w, acc[1][3]);
        acc[2][0] = fmaf(av.z, bv.x, acc[2][0]);
        acc[2][1] = fmaf(av.z, bv.y, acc[2][1]);
        acc[2][2] = fmaf(av.z, bv.z, acc[2][2]);
        acc[2][3] = fmaf(av.z, bv.w, acc[2][3]);
        acc[3][0] = fmaf(av.w, bv.x, acc[3][0]);
        acc[3][1] = fmaf(av.w, bv.y, acc[3][1]);
        acc[3][2] = fmaf(av.w, bv.z, acc[3][2]);
        acc[3][3] = fmaf(av.w, bv.w, acc[3][3]);
      }
    }

#pragma unroll
    for (int j = 0; j < 4; ++j) {
#pragma unroll
      for (int s = 0; s < 4; ++s) {
        const float v = acc[j][s];
        const int m = mbase + mi * 4 + s;
        const bool b0 = v > tv[j][0];
        const bool b1 = v > tv[j][1];
        const bool b2 = v > tv[j][2];
        const bool b3 = v > tv[j][3];
        tv[j][3] = b2 ? tv[j][2] : (b3 ? v : tv[j][3]);
        ti[j][3] = b2 ? ti[j][2] : (b3 ? m : ti[j][3]);
        tv[j][2] = b1 ? tv[j][1] : (b2 ? v : tv[j][2]);
        ti[j][2] = b1 ? ti[j][1] : (b2 ? m : ti[j][2]);
        tv[j][1] = b0 ? tv[j][0] : (b1 ? v : tv[j][1]);
        ti[j][1] = b0 ? ti[j][0] : (b1 ? m : ti[j][1]);
        tv[j][0] = b0 ? v : tv[j][0];
        ti[j][0] = b0 ? m : ti[j][0];
      }
    }
  }

  __syncthreads();
  int* idx_lds = (int*)B_lds;
#pragma unroll
  for (int j = 0; j < 4; ++j)
#pragma unroll
    for (int s = 0; s < 4; ++s)
      idx_lds[(qi * 4 + j) * 128 + mi * 4 + s] = ti[j][s];
  __syncthreads();

  double* pv = (double*)A_lds;
  int* piL = (int*)(A_lds + 4096);
  {
    const int r = t >> 3;
    const int slot = t & 7;
    const float* qrow = qp + (size_t)r * KD;
    double bv[4];
    int bi[4];
#pragma unroll
    for (int e = 0; e < 4; ++e) { bv[e] = -DBL_MAX; bi[e] = 0x7fffffff; }

    for (int c = 0; c < 16; ++c) {
      const int m = idx_lds[r * 128 + slot * 16 + c];
      const float* irow = ip + (size_t)m * KD;
      double s0 = 0.0, s1 = 0.0, s2 = 0.0, s3 = 0.0;
#pragma unroll
      for (int k = 0; k < KD; k += 4) {
        const float4 xv = *(const float4*)(qrow + k);
        const float4 yv = *(const float4*)(irow + k);
        s0 = fma((double)xv.x, (double)yv.x, s0);
        s1 = fma((double)xv.y, (double)yv.y, s1);
        s2 = fma((double)xv.z, (double)yv.z, s2);
        s3 = fma((double)xv.w, (double)yv.w, s3);
      }
      const double v = (s0 + s1) + (s2 + s3);
      const bool b0 = BETTER64(v, m, bv[0], bi[0]);
      const bool b1 = BETTER64(v, m, bv[1], bi[1]);
      const bool b2 = BETTER64(v, m, bv[2], bi[2]);
      const bool b3 = BETTER64(v, m, bv[3], bi[3]);
      bv[3] = b2 ? bv[2] : (b3 ? v : bv[3]);
      bi[3] = b2 ? bi[2] : (b3 ? m : bi[3]);
      bv[2] = b1 ? bv[1] : (b2 ? v : bv[2]);
      bi[2] = b1 ? bi[1] : (b2 ? m : bi[2]);
      bv[1] = b0 ? bv[0] : (b1 ? v : bv[1]);
      bi[1] = b0 ? bi[0] : (b1 ? m : bi[1]);
      bv[0] = b0 ? v : bv[0];
      bi[0] = b0 ? m : bi[0];
    }
#pragma unroll
    for (int e = 0; e < 4; ++e) {
      pv[t * 4 + e] = bv[e];
      piL[t * 4 + e] = bi[e];
    }
  }
  __syncthreads();

  if (t < QT) {
    double fv[4];
    int fi[4];
#pragma unroll
    for (int e = 0; e < 4; ++e) { fv[e] = -DBL_MAX; fi[e] = 0x7fffffff; }
    for (int sl = 0; sl < 8; ++sl) {
#pragma unroll
      for (int e = 0; e < 4; ++e) {
        const double v = pv[(t * 8 + sl) * 4 + e];
        const int m = piL[(t * 8 + sl) * 4 + e];
        const bool b0 = BETTER64(v, m, fv[0], fi[0]);
        const bool b1 = BETTER64(v, m, fv[1], fi[1]);
        const bool b2 = BETTER64(v, m, fv[2], fi[2]);
        const bool b3 = BETTER64(v, m, fv[3], fi[3]);
        fv[3] = b2 ? fv[2] : (b3 ? v : fv[3]);
        fi[3] = b2 ? fi[2] : (b3 ? m : fi[3]);
        fv[2] = b1 ? fv[1] : (b2 ? v : fv[2]);
        fi[2] = b1 ? fi[1] : (b2 ? m : fi[2]);
        fv[1] = b0 ? fv[0] : (b1 ? v : fv[1]);
        fi[1] = b0 ? fi[0] : (b1 ? m : fi[1]);
        fv[0] = b0 ? v : fv[0];
        fi[0] = b0 ? m : fi[0];
      }
    }
    int4 o;
    o.x = fi[0]; o.y = fi[1]; o.z = fi[2]; o.w = fi[3];
    *(int4*)(out + ((size_t)b * NQ + qbase + t) * 4) = o;
  }
}

extern "C" void kernel_launch(void* const* d_in, const int* in_sizes, int n_in,
                              void* d_out, int out_size, void* d_ws, size_t ws_size,
                              hipStream_t stream) {
  const float* qry = (const float*)d_in[0];  // (4, 4096, 128) fp32
  const float* img = (const float*)d_in[1];  // (4, 8192, 128) fp32
  int* out = (int*)d_out;                    // (4, 4096, 4) int32

  const size_t qbBytes = (size_t)NBATCH * NQ * KD * sizeof(ushort_t);  // 4 MB
  const size_t ibBytes = (size_t)NBATCH * NM * KD * sizeof(ushort_t);  // 8 MB

  if (ws_size >= qbBytes + ibBytes) {
    ushort_t* qb = (ushort_t*)d_ws;
    int4* ib = (int4*)((char*)d_ws + qbBytes);
    wr_cvt<<<3072, 256, 0, stream>>>(qry, img, qb, ib);
    wr_mfma<<<256, 512, 0, stream>>>(qry, img, qb, ib, out);
  } else {
    wr_main<<<NBATCH * (NQ / QT), NTHREADS, 0, stream>>>(qry, img, out);
  }
}

// Round 8
// 138.809 us; speedup vs baseline: 1.7390x; 1.1558x over previous
//
#include <hip/hip_runtime.h>
#include <float.h>
#include <stdint.h>

// WindowRouting: out[b][q][0..3] = indices of top-4 of (Q[b,q,:] . I[b,m,:]) over m.
// Scale dropped (order-preserving).
//
// R16 = R11 (proven 133.56us total, wr_mfma 69.7us, VGPR 100) + ONE change:
// software-pipelined selection, one step behind MFMAs, via statically-named
// dual accumulators aE/aO (period-6 unroll over 3-buffer ring x 2 parities).
// R9's idea WITHOUT R9's pointer-passed arrays (which defeated SROA -> 176MB
// scratch). R15 lesson: the step loop is latency-bound, not VALU-issue-bound
// (cutting 96->32 select ops/step made it 38us SLOWER); so remove the
// MFMA->select dependency from the per-step critical path instead.
// Per step: 16 MFMAs (parity X) -> 4 ring loads -> select parity !X (operands
// one full step old = complete). Select h-order preserved (vb -= 16/select)
// -> packed keys identical -> R11 epilogue byte-identical.
// Sentinels: VGPR <= ~125, WRITE_SIZE ~256KB (spill), FETCH ~27MB.
//
// K0 (wr_cvt): fp32 -> bf16, DIRECT (no LDS/sync).
// K1 (wr_mfma): 256 blocks x 512 thr, launch_bounds(512,1). Block = 64 q x all
//   8192 m; wave = m-eighth (64 half-tiles of 16 m); 4 q-strips of 16 (bfrag
//   pinned, 64 VGPRs); 3-deep rotating 16-reg image ring; 16 MFMAs consume R
//   before refill. Packed keys (low 11 bits = 2047 - m_local); running top-4
//   via v_max + 3x v_med3 per strip; quad-tree shfl merge (snapshot-first);
//   32 cand/row -> rank-select top-8 -> fp64 refine -> exact top-4.
// Fallback: fp32 LDS-tiled kernel if ws too small.

#define NBATCH 4
#define NQ 4096
#define NM 8192
#define KD 128

typedef unsigned short ushort_t;
typedef __attribute__((ext_vector_type(8))) short bf16x8;
typedef __attribute__((ext_vector_type(4))) float f32x4;

#define BETTER64(v, i, w, j) (((v) > (w)) || ((v) == (w) && (i) < (j)))

__device__ inline float fmed3(float a, float b, float c) {
#if __has_builtin(__builtin_amdgcn_fmed3f)
  return __builtin_amdgcn_fmed3f(a, b, c);
#else
  return fmaxf(fminf(a, b), fminf(fmaxf(a, b), c));
#endif
}

__device__ inline ushort_t f2bf(float f) {
  unsigned u = __float_as_uint(f);
  u += 0x7fffu + ((u >> 16) & 1u);  // RNE
  return (ushort_t)(u >> 16);
}

__device__ inline unsigned pk2(float a, float b) {
  return (unsigned)f2bf(a) | ((unsigned)f2bf(b) << 16);
}

// ---------------- K0: direct convert + swizzle (no LDS) ----------------
// ib flat int4 index t (within batch): tt = tile*512 + htl*256 + ks*64 + l
//   -> row m = tile*32 + htl*16 + (l&15), k0 = ks*32 + (l>>4)*8, 8 bf16 elems.
__global__ __launch_bounds__(256) void wr_cvt(const float* __restrict__ qry,
                                              const float* __restrict__ img,
                                              ushort_t* __restrict__ qb,
                                              int4* __restrict__ ib) {
  const int t = (int)blockIdx.x * 256 + (int)threadIdx.x;  // 0..786431
  if (t < 524288) {
    // image: one ib int4 per thread
    const int b = t >> 17;
    const int tt = t & 131071;
    const int tile = tt >> 9;
    const int n = tt & 511;
    const int l = n & 63;
    const int m = tile * 32 + (n >> 8) * 16 + (l & 15);
    const int k0 = ((n >> 6) & 3) * 32 + ((l >> 4) & 3) * 8;
    const float* src = img + ((size_t)(b * NM + m)) * KD + k0;
    const float4 v0 = *(const float4*)(src);
    const float4 v1 = *(const float4*)(src + 4);
    int4 o;
    o.x = (int)pk2(v0.x, v0.y);
    o.y = (int)pk2(v0.z, v0.w);
    o.z = (int)pk2(v1.x, v1.y);
    o.w = (int)pk2(v1.z, v1.w);
    ib[t] = o;
  } else {
    // query: 8 elements per thread, linear
    const int u = t - 524288;  // 0..262143
    const float4 v0 = ((const float4*)qry)[2 * u];
    const float4 v1 = ((const float4*)qry)[2 * u + 1];
    int4 o;
    o.x = (int)pk2(v0.x, v0.y);
    o.y = (int)pk2(v0.z, v0.w);
    o.z = (int)pk2(v1.x, v1.y);
    o.w = (int)pk2(v1.z, v1.w);
    ((int4*)qb)[u] = o;
  }
}

// ---------------- K1: MFMA screen (pipelined select) + fp64 refine ----------------
__global__ __launch_bounds__(512, 1) void wr_mfma(const float* __restrict__ qry,
                                                  const float* __restrict__ img,
                                                  const ushort_t* __restrict__ qb,
                                                  const int4* __restrict__ ib,
                                                  int* __restrict__ out) {
  const int bid = (int)blockIdx.x;               // 0..255
  const int b = (bid & 7) >> 1;                  // batch pinned to XCD pair
  const int qt = ((bid >> 3) << 1) | (bid & 1);  // 0..63
  const int qbase = qt * 64;

  const int tid = (int)threadIdx.x;
  const int lane = tid & 63;
  const int w = tid >> 6;        // 0..7 -> m-eighth (64 half-tiles of 16 m)
  const int q15 = lane & 15;
  const int quad = lane >> 4;    // 0..3

  const ushort_t* Qb = qb + ((size_t)b * NQ + qbase) * KD;
  const int4* ibc = ib + (size_t)b * 131072;

  // query fragments pinned: 4 strips of 16 q. B[n=q15][k = ks*32 + quad*8 + j]
  bf16x8 bfrag[4][4];  // [strip][ks] -> 64 VGPRs
#pragma unroll
  for (int s = 0; s < 4; ++s)
#pragma unroll
    for (int ks = 0; ks < 4; ++ks)
      bfrag[s][ks] =
          *(const bf16x8*)(Qb + (size_t)(s * 16 + q15) * KD + ks * 32 + quad * 8);

  float tch[4][4];  // one packed-key top-4 chain per strip
#pragma unroll
  for (int s = 0; s < 4; ++s)
#pragma unroll
    for (int e = 0; e < 4; ++e) tch[s][e] = -FLT_MAX;

  bf16x8 B0[4], B1[4], B2[4];  // 3-deep ring, 16 regs each

  auto loadH = [&](bf16x8* R, int h) {
    const int4* p = ibc + (((w * 64 + h) << 8) + lane);
#pragma unroll
    for (int ks = 0; ks < 4; ++ks) R[ks] = *(const bf16x8*)(p + ks * 64);
  };

  int hl = 3;
  int vb = 2047 - 4 * quad;  // key base; m_local = 16*h + 4*quad + r  (< 1024)

  f32x4 aE[4], aO[4];  // dual accumulators, statically named (no ptr indirection)

// MFMA_STEP(R, ACC): 16 MFMAs of current half-tile into ACC, then ring refill.
// All 16 MFMAs consume R before the refill (ring-reuse WAR hazard).
#define MFMA_STEP(R, ACC)                                                     \
  {                                                                           \
    _Pragma("unroll") for (int s = 0; s < 4; ++s) ACC[s] = {0.f, 0.f, 0.f, 0.f}; \
    _Pragma("unroll") for (int ks = 0; ks < 4; ++ks)                          \
        _Pragma("unroll") for (int s = 0; s < 4; ++s)                         \
            ACC[s] = __builtin_amdgcn_mfma_f32_16x16x32_bf16(                 \
                R[ks], bfrag[s][ks], ACC[s], 0, 0, 0);                        \
    if (hl < 64) loadH(R, hl);                                                \
    ++hl;                                                                     \
  }

// SELECT_STEP(ACC): insert 16 packed keys of the PREVIOUS step's scores.
// Executes under the current step's MFMA/load shadow (no data dependency).
#define SELECT_STEP(ACC)                                                      \
  {                                                                           \
    _Pragma("unroll") for (int s = 0; s < 4; ++s) {                           \
      _Pragma("unroll") for (int r = 0; r < 4; ++r) {                         \
        const unsigned kr = (unsigned)(vb - r);                               \
        const float k =                                                       \
            __uint_as_float((__float_as_uint(ACC[s][r]) & 0xFFFFF800u) | kr); \
        tch[s][3] = fmed3(k, tch[s][2], tch[s][3]);                           \
        tch[s][2] = fmed3(k, tch[s][1], tch[s][2]);                           \
        tch[s][1] = fmed3(k, tch[s][0], tch[s][1]);                           \
        tch[s][0] = fmaxf(tch[s][0], k);                                      \
      }                                                                       \
    }                                                                         \
    vb -= 16;                                                                 \
  }

  loadH(B0, 0);
  loadH(B1, 1);
  loadH(B2, 2);
  MFMA_STEP(B0, aE);  // h=0
  // period-6 steady state: ring period 3 x parity period 2
  for (int g = 0; g < 10; ++g) {  // h = 6g+1 .. 6g+6
    MFMA_STEP(B1, aO); SELECT_STEP(aE);
    MFMA_STEP(B2, aE); SELECT_STEP(aO);
    MFMA_STEP(B0, aO); SELECT_STEP(aE);
    MFMA_STEP(B1, aE); SELECT_STEP(aO);
    MFMA_STEP(B2, aO); SELECT_STEP(aE);
    MFMA_STEP(B0, aE); SELECT_STEP(aO);
  }
  MFMA_STEP(B1, aO); SELECT_STEP(aE);  // h=61
  MFMA_STEP(B2, aE); SELECT_STEP(aO);  // h=62
  MFMA_STEP(B0, aO); SELECT_STEP(aE);  // h=63 (hl=67: no refill)
  SELECT_STEP(aO);                     // h=63 scores

#undef MFMA_STEP
#undef SELECT_STEP

  // ---- quad-tree merge per strip (snapshot donor regs BEFORE mutating) ----
#pragma unroll
  for (int s = 0; s < 4; ++s) {
    float k4[4];
#pragma unroll
    for (int e = 0; e < 4; ++e) k4[e] = __shfl_down(tch[s][e], 32, 64);
#pragma unroll
    for (int e = 0; e < 4; ++e) {
      const float k = k4[e];
      tch[s][3] = fmed3(k, tch[s][2], tch[s][3]);
      tch[s][2] = fmed3(k, tch[s][1], tch[s][2]);
      tch[s][1] = fmed3(k, tch[s][0], tch[s][1]);
      tch[s][0] = fmaxf(tch[s][0], k);
    }
#pragma unroll
    for (int e = 0; e < 4; ++e) k4[e] = __shfl_down(tch[s][e], 16, 64);
#pragma unroll
    for (int e = 0; e < 4; ++e) {
      const float k = k4[e];
      tch[s][3] = fmed3(k, tch[s][2], tch[s][3]);
      tch[s][2] = fmed3(k, tch[s][1], tch[s][2]);
      tch[s][1] = fmed3(k, tch[s][0], tch[s][1]);
      tch[s][0] = fmaxf(tch[s][0], k);
    }
  }

  // ---- 32 candidates per q-row (8 eighths x 4), 64 rows ----
  __shared__ float ck[64][33];
  __shared__ int top8[64][8];
  __shared__ double pd[64][8];
  __shared__ int pi[64][8];

  if (lane < 16) {
#pragma unroll
    for (int s = 0; s < 4; ++s)
#pragma unroll
      for (int e = 0; e < 4; ++e) ck[s * 16 + q15][w * 4 + e] = tch[s][e];
  }
  __syncthreads();

  // ---- rank-select top-8 of 32 packed keys per row (ranks unique) ----
  for (int p = tid; p < 2048; p += 512) {
    const int q = p >> 5;
    const int j = p & 31;
    const float k = ck[q][j];
    int rank = 0;
#pragma unroll 8
    for (int i = 0; i < 32; ++i) {
      const float o = ck[q][i];
      rank += (o > k) || (o == k && i < j);
    }
    if (rank < 8) {
      const unsigned bits = __float_as_uint(k);
      top8[q][rank] = (j >> 2) * 1024 + 2047 - (int)(bits & 0x7FFu);
    }
  }
  __syncthreads();

  // ---- fp64 refine: one candidate per thread (64 rows x 8) ----
  {
    const int q = tid >> 3;
    const int slot = tid & 7;
    const int m = top8[q][slot];
    const float* qrow = qry + ((size_t)b * NQ + qbase + q) * KD;
    const float* irow = img + ((size_t)b * NM + m) * KD;
    double s0 = 0.0, s1 = 0.0, s2 = 0.0, s3 = 0.0;
#pragma unroll
    for (int k = 0; k < KD; k += 4) {
      const float4 xv = *(const float4*)(qrow + k);
      const float4 yv = *(const float4*)(irow + k);
      s0 = fma((double)xv.x, (double)yv.x, s0);
      s1 = fma((double)xv.y, (double)yv.y, s1);
      s2 = fma((double)xv.z, (double)yv.z, s2);
      s3 = fma((double)xv.w, (double)yv.w, s3);
    }
    pd[q][slot] = (s0 + s1) + (s2 + s3);
    pi[q][slot] = m;
  }
  __syncthreads();

  // ---- exact top-4 of 8 refined, (value desc, index asc) ----
  if (tid < 64) {
    const int q = tid;
    double fv[4];
    int fi[4];
#pragma unroll
    for (int e = 0; e < 4; ++e) { fv[e] = -DBL_MAX; fi[e] = 0x7fffffff; }
    for (int sl = 0; sl < 8; ++sl) {
      const double v = pd[q][sl];
      const int m = pi[q][sl];
      const bool b0 = BETTER64(v, m, fv[0], fi[0]);
      const bool b1 = BETTER64(v, m, fv[1], fi[1]);
      const bool b2 = BETTER64(v, m, fv[2], fi[2]);
      const bool b3 = BETTER64(v, m, fv[3], fi[3]);
      fv[3] = b2 ? fv[2] : (b3 ? v : fv[3]);
      fi[3] = b2 ? fi[2] : (b3 ? m : fi[3]);
      fv[2] = b1 ? fv[1] : (b2 ? v : fv[2]);
      fi[2] = b1 ? fi[1] : (b2 ? m : fi[2]);
      fv[1] = b0 ? fv[0] : (b1 ? v : fv[1]);
      fi[1] = b0 ? fi[0] : (b1 ? m : fi[1]);
      fv[0] = b0 ? v : fv[0];
      fi[0] = b0 ? m : fi[0];
    }
    int4 o;
    o.x = fi[0]; o.y = fi[1]; o.z = fi[2]; o.w = fi[3];
    *(int4*)(out + ((size_t)b * NQ + qbase + q) * 4) = o;
  }
}

// ---------------- Fallback: fp32 LDS-tiled kernel (ws too small) ----------------
#define QT 64
#define MT 128
#define KC 64
#define NTHREADS 512

__global__ __launch_bounds__(NTHREADS) void wr_main(const float* __restrict__ qry,
                                                    const float* __restrict__ img,
                                                    int* __restrict__ out) {
  __shared__ __align__(16) float A_lds[KD * QT];
  __shared__ __align__(16) float B_lds[KC * MT];

  const int t = (int)threadIdx.x;
  const int b = (int)blockIdx.x >> 6;
  const int qbase = ((int)blockIdx.x & 63) * QT;

  const float* qp = qry + ((size_t)b * NQ + qbase) * KD;
  const float* ip = img + (size_t)b * NM * KD;

  {
    const int r = t >> 3;
    const int kc = t & 7;
    const float* src = qp + (size_t)r * KD;
#pragma unroll
    for (int i = 0; i < 4; ++i) {
      const int k0 = kc * 4 + i * 32;
      const float4 v = *(const float4*)(src + k0);
      A_lds[(k0 + 0) * QT + r] = v.x;
      A_lds[(k0 + 1) * QT + r] = v.y;
      A_lds[(k0 + 2) * QT + r] = v.z;
      A_lds[(k0 + 3) * QT + r] = v.w;
    }
  }

  const int qi = t >> 5;
  const int mi = t & 31;

  float tv[4][4];
  int ti[4][4];
#pragma unroll
  for (int j = 0; j < 4; ++j)
#pragma unroll
    for (int s = 0; s < 4; ++s) { tv[j][s] = -FLT_MAX; ti[j][s] = 0x7fffffff; }

  for (int tile = 0; tile < NM / MT; ++tile) {
    const int mbase = tile * MT;
    float acc[4][4];
#pragma unroll
    for (int j = 0; j < 4; ++j)
#pragma unroll
      for (int s = 0; s < 4; ++s) acc[j][s] = 0.0f;

    for (int kb = 0; kb < KD; kb += KC) {
      __syncthreads();
      {
        const int r = t >> 2;
        const int kc = t & 3;
        const float* src = ip + (size_t)(mbase + r) * KD + kb;
#pragma unroll
        for (int i = 0; i < 4; ++i) {
          const int k0 = kc * 4 + i * 16;
          const float4 v = *(const float4*)(src + k0);
          B_lds[(k0 + 0) * MT + r] = v.x;
          B_lds[(k0 + 1) * MT + r] = v.y;
          B_lds[(k0 + 2) * MT + r] = v.z;
          B_lds[(k0 + 3) * MT + r] = v.w;
        }
      }
      __syncthreads();

#pragma unroll 8
      for (int k = 0; k < KC; ++k) {
        const float4 av = *(const float4*)&A_lds[(kb + k) * QT + qi * 4];
        const float4 bv = *(const float4*)&B_lds[k * MT + mi * 4];
        acc[0][0] = fmaf(av.x, bv.x, acc[0][0]);
        acc[0][1] = fmaf(av.x, bv.y, acc[0][1]);
        acc[0][2] = fmaf(av.x, bv.z, acc[0][2]);
        acc[0][3] = fmaf(av.x, bv.w, acc[0][3]);
        acc[1][0] = fmaf(av.y, bv.x, acc[1][0]);
        acc[1][1] = fmaf(av.y, bv.y, acc[1][1]);
        acc[1][2] = fmaf(av.y, bv.z, acc[1][2]);
        acc[1][3] = fmaf(av.y, bv.w, acc[1][3]);
        acc[2][0] = fmaf(av.z, bv.x, acc[2][0]);
        acc[2][1] = fmaf(av.z, bv.y, acc[2][1]);
        acc[2][2] = fmaf(av.z, bv.z, acc[2][2]);
        acc[2][3] = fmaf(av.z, bv.w, acc[2][3]);
        acc[3][0] = fmaf(av.w, bv.x, acc[3][0]);
        acc[3][1] = fmaf(av.w, bv.y, acc[3][1]);
        acc[3][2] = fmaf(av.w, bv.z, acc[3][2]);
        acc[3][3] = fmaf(av.w, bv.w, acc[3][3]);
      }
    }

#pragma unroll
    for (int j = 0; j < 4; ++j) {
#pragma unroll
      for (int s = 0; s < 4; ++s) {
        const float v = acc[j][s];
        const int m = mbase + mi * 4 + s;
        const bool b0 = v > tv[j][0];
        const bool b1 = v > tv[j][1];
        const bool b2 = v > tv[j][2];
        const bool b3 = v > tv[j][3];
        tv[j][3] = b2 ? tv[j][2] : (b3 ? v : tv[j][3]);
        ti[j][3] = b2 ? ti[j][2] : (b3 ? m : ti[j][3]);
        tv[j][2] = b1 ? tv[j][1] : (b2 ? v : tv[j][2]);
        ti[j][2] = b1 ? ti[j][1] : (b2 ? m : ti[j][2]);
        tv[j][1] = b0 ? tv[j][0] : (b1 ? v : tv[j][1]);
        ti[j][1] = b0 ? ti[j][0] : (b1 ? m : ti[j][1]);
        tv[j][0] = b0 ? v : tv[j][0];
        ti[j][0] = b0 ? m : ti[j][0];
      }
    }
  }

  __syncthreads();
  int* idx_lds = (int*)B_lds;
#pragma unroll
  for (int j = 0; j < 4; ++j)
#pragma unroll
    for (int s = 0; s < 4; ++s)
      idx_lds[(qi * 4 + j) * 128 + mi * 4 + s] = ti[j][s];
  __syncthreads();

  double* pv = (double*)A_lds;
  int* piL = (int*)(A_lds + 4096);
  {
    const int r = t >> 3;
    const int slot = t & 7;
    const float* qrow = qp + (size_t)r * KD;
    double bv[4];
    int bi[4];
#pragma unroll
    for (int e = 0; e < 4; ++e) { bv[e] = -DBL_MAX; bi[e] = 0x7fffffff; }

    for (int c = 0; c < 16; ++c) {
      const int m = idx_lds[r * 128 + slot * 16 + c];
      const float* irow = ip + (size_t)m * KD;
      double s0 = 0.0, s1 = 0.0, s2 = 0.0, s3 = 0.0;
#pragma unroll
      for (int k = 0; k < KD; k += 4) {
        const float4 xv = *(const float4*)(qrow + k);
        const float4 yv = *(const float4*)(irow + k);
        s0 = fma((double)xv.x, (double)yv.x, s0);
        s1 = fma((double)xv.y, (double)yv.y, s1);
        s2 = fma((double)xv.z, (double)yv.z, s2);
        s3 = fma((double)xv.w, (double)yv.w, s3);
      }
      const double v = (s0 + s1) + (s2 + s3);
      const bool b0 = BETTER64(v, m, bv[0], bi[0]);
      const bool b1 = BETTER64(v, m, bv[1], bi[1]);
      const bool b2 = BETTER64(v, m, bv[2], bi[2]);
      const bool b3 = BETTER64(v, m, bv[3], bi[3]);
      bv[3] = b2 ? bv[2] : (b3 ? v : bv[3]);
      bi[3] = b2 ? bi[2] : (b3 ? m : bi[3]);
      bv[2] = b1 ? bv[1] : (b2 ? v : bv[2]);
      bi[2] = b1 ? bi[1] : (b2 ? m : bi[2]);
      bv[1] = b0 ? bv[0] : (b1 ? v : bv[1]);
      bi[1] = b0 ? bi[0] : (b1 ? m : bi[1]);
      bv[0] = b0 ? v : bv[0];
      bi[0] = b0 ? m : bi[0];
    }
#pragma unroll
    for (int e = 0; e < 4; ++e) {
      pv[t * 4 + e] = bv[e];
      piL[t * 4 + e] = bi[e];
    }
  }
  __syncthreads();

  if (t < QT) {
    double fv[4];
    int fi[4];
#pragma unroll
    for (int e = 0; e < 4; ++e) { fv[e] = -DBL_MAX; fi[e] = 0x7fffffff; }
    for (int sl = 0; sl < 8; ++sl) {
#pragma unroll
      for (int e = 0; e < 4; ++e) {
        const double v = pv[(t * 8 + sl) * 4 + e];
        const int m = piL[(t * 8 + sl) * 4 + e];
        const bool b0 = BETTER64(v, m, fv[0], fi[0]);
        const bool b1 = BETTER64(v, m, fv[1], fi[1]);
        const bool b2 = BETTER64(v, m, fv[2], fi[2]);
        const bool b3 = BETTER64(v, m, fv[3], fi[3]);
        fv[3] = b2 ? fv[2] : (b3 ? v : fv[3]);
        fi[3] = b2 ? fi[2] : (b3 ? m : fi[3]);
        fv[2] = b1 ? fv[1] : (b2 ? v : fv[2]);
        fi[2] = b1 ? fi[1] : (b2 ? m : fi[2]);
        fv[1] = b0 ? fv[0] : (b1 ? v : fv[1]);
        fi[1] = b0 ? fi[0] : (b1 ? m : fi[1]);
        fv[0] = b0 ? v : fv[0];
        fi[0] = b0 ? m : fi[0];
      }
    }
    int4 o;
    o.x = fi[0]; o.y = fi[1]; o.z = fi[2]; o.w = fi[3];
    *(int4*)(out + ((size_t)b * NQ + qbase + t) * 4) = o;
  }
}

extern "C" void kernel_launch(void* const* d_in, const int* in_sizes, int n_in,
                              void* d_out, int out_size, void* d_ws, size_t ws_size,
                              hipStream_t stream) {
  const float* qry = (const float*)d_in[0];  // (4, 4096, 128) fp32
  const float* img = (const float*)d_in[1];  // (4, 8192, 128) fp32
  int* out = (int*)d_out;                    // (4, 4096, 4) int32

  const size_t qbBytes = (size_t)NBATCH * NQ * KD * sizeof(ushort_t);  // 4 MB
  const size_t ibBytes = (size_t)NBATCH * NM * KD * sizeof(ushort_t);  // 8 MB

  if (ws_size >= qbBytes + ibBytes) {
    ushort_t* qb = (ushort_t*)d_ws;
    int4* ib = (int4*)((char*)d_ws + qbBytes);
    wr_cvt<<<3072, 256, 0, stream>>>(qry, img, qb, ib);
    wr_mfma<<<256, 512, 0, stream>>>(qry, img, qb, ib, out);
  } else {
    wr_main<<<NBATCH * (NQ / QT), NTHREADS, 0, stream>>>(qry, img, out);
  }
}

// Round 9
// 129.542 us; speedup vs baseline: 1.8634x; 1.0715x over previous
//
#include <hip/hip_runtime.h>
#include <float.h>
#include <stdint.h>

// WindowRouting: out[b][q][0..3] = indices of top-4 of (Q[b,q,:] . I[b,m,:]) over m.
// Scale dropped (order-preserving).
//
// R17: 32x32x16 MFMA screen -> HALF the steps. Evidence: ~70us screen loop is
// invariant under waves (R13), worse with fewer select ops (R15), unchanged
// with dependency-broken select (R16) -> binding term is a fixed per-step cost
// (~700cy/step-slot unattributed). This round: per step = 32 m x 64 q x K=128
// via 16x mfma_f32_32x32x16_bf16 (2x FLOP/MFMA, 15% faster rate), 8x 16B
// coalesced loads (2-deep ring), 32 key-inserts. 32 steps vs 64: same total
// FLOP/ops/bytes, half the step boundaries.
// Layouts: A row=lane&31, k=ks*16+(lane>>5)*8 (mirrors proven 16x16 pattern);
// C/D row=(reg&3)+8*(reg>>2)+4*(lane>>5), col=lane&31 (HW-verified m74/m101).
// Keys: low 11 bits = 2047 - m_local, m_local = tile*32+row < 1024. Epilogue
// (rank-select top-8 of 32, fp64 refine, exact top-4) = R11 verbatim.
// Sentinels: VGPR <= ~210, WRITE_SIZE ~256KB, FETCH ~27MB.
//
// K0 (wr_cvt): fp32 -> bf16, DIRECT (no LDS/sync), emits the 32x32-fragment-
//   linear layouts for image (A) and query (B).
// Fallback: fp32 LDS-tiled kernel if ws too small (unchanged).

#define NBATCH 4
#define NQ 4096
#define NM 8192
#define KD 128

typedef unsigned short ushort_t;
typedef __attribute__((ext_vector_type(8))) short bf16x8;
typedef __attribute__((ext_vector_type(4))) float f32x4;
typedef __attribute__((ext_vector_type(16))) float f32x16;

#define BETTER64(v, i, w, j) (((v) > (w)) || ((v) == (w) && (i) < (j)))

__device__ inline float fmed3(float a, float b, float c) {
#if __has_builtin(__builtin_amdgcn_fmed3f)
  return __builtin_amdgcn_fmed3f(a, b, c);
#else
  return fmaxf(fminf(a, b), fminf(fmaxf(a, b), c));
#endif
}

__device__ inline ushort_t f2bf(float f) {
  unsigned u = __float_as_uint(f);
  u += 0x7fffu + ((u >> 16) & 1u);  // RNE
  return (ushort_t)(u >> 16);
}

__device__ inline unsigned pk2(float a, float b) {
  return (unsigned)f2bf(a) | ((unsigned)f2bf(b) << 16);
}

// ---------------- K0: direct convert + swizzle (no LDS) ----------------
// Image ib (per batch 131072 int4): idx = e*16384 + tile*512 + ks*64 + l
//   -> m = e*1024 + tile*32 + (l&31), k = ks*16 + (l>>5)*8, 8 bf16 elems.
// Query qb (per batch 65536 int4): idx = qt*1024 + h*512 + ks*64 + l
//   -> q = qt*64 + h*32 + (l&31), k = ks*16 + (l>>5)*8, 8 bf16 elems.
__global__ __launch_bounds__(256) void wr_cvt(const float* __restrict__ qry,
                                              const float* __restrict__ img,
                                              int4* __restrict__ qb,
                                              int4* __restrict__ ib) {
  const int t = (int)blockIdx.x * 256 + (int)threadIdx.x;  // 0..786431
  if (t < 524288) {
    // image: one ib int4 per thread
    const int b = t >> 17;
    const int tt = t & 131071;
    const int e = tt >> 14;
    const int r = tt & 16383;
    const int tile = r >> 9;
    const int ks = (r >> 6) & 7;
    const int l = r & 63;
    const int m = e * 1024 + tile * 32 + (l & 31);
    const int k0 = ks * 16 + (l >> 5) * 8;
    const float* src = img + ((size_t)(b * NM + m)) * KD + k0;
    const float4 v0 = *(const float4*)(src);
    const float4 v1 = *(const float4*)(src + 4);
    int4 o;
    o.x = (int)pk2(v0.x, v0.y);
    o.y = (int)pk2(v0.z, v0.w);
    o.z = (int)pk2(v1.x, v1.y);
    o.w = (int)pk2(v1.z, v1.w);
    ib[t] = o;
  } else {
    // query: one qb int4 per thread
    const int u = t - 524288;  // 0..262143
    const int b = u >> 16;
    const int uu = u & 65535;
    const int qt = uu >> 10;
    const int r = uu & 1023;
    const int h = r >> 9;
    const int ks = (r >> 6) & 7;
    const int l = r & 63;
    const int q = qt * 64 + h * 32 + (l & 31);
    const int k0 = ks * 16 + (l >> 5) * 8;
    const float* src = qry + ((size_t)(b * NQ + q)) * KD + k0;
    const float4 v0 = *(const float4*)(src);
    const float4 v1 = *(const float4*)(src + 4);
    int4 o;
    o.x = (int)pk2(v0.x, v0.y);
    o.y = (int)pk2(v0.z, v0.w);
    o.z = (int)pk2(v1.x, v1.y);
    o.w = (int)pk2(v1.z, v1.w);
    qb[u] = o;
  }
}

// ---------------- K1: 32x32 MFMA screen + fp64 refine ----------------
__global__ __launch_bounds__(512, 1) void wr_mfma(const float* __restrict__ qry,
                                                  const float* __restrict__ img,
                                                  const int4* __restrict__ qb,
                                                  const int4* __restrict__ ib,
                                                  int* __restrict__ out) {
  const int bid = (int)blockIdx.x;               // 0..255
  const int b = (bid & 7) >> 1;                  // batch pinned to XCD pair
  const int qt = ((bid >> 3) << 1) | (bid & 1);  // 0..63
  const int qbase = qt * 64;

  const int tid = (int)threadIdx.x;
  const int lane = tid & 63;
  const int w = tid >> 6;        // 0..7 -> m-eighth (32 tiles of 32 m)
  const int l31 = lane & 31;
  const int lh = lane >> 5;      // 0..1

  const int4* Qb = qb + (size_t)b * 65536 + qt * 1024;
  const int4* ibc = ib + (size_t)b * 131072 + w * 16384;

  // query fragments pinned: 2 q-halves x 8 k-slices. B[k=ks*16+lh*8+j][q=l31]
  bf16x8 bfrag[2][8];  // 64 VGPRs
#pragma unroll
  for (int h = 0; h < 2; ++h)
#pragma unroll
    for (int ks = 0; ks < 8; ++ks)
      bfrag[h][ks] = *(const bf16x8*)&Qb[h * 512 + ks * 64 + lane];

  float tch[2][4];  // one packed-key top-4 chain per q-half
#pragma unroll
  for (int c = 0; c < 2; ++c)
#pragma unroll
    for (int e = 0; e < 4; ++e) tch[c][e] = -FLT_MAX;

  bf16x8 A0[8], A1[8];  // 2-deep ring, 32 VGPRs each

  auto loadA = [&](bf16x8* A, int t) {
    const int4* p = ibc + t * 512 + lane;
#pragma unroll
    for (int ks = 0; ks < 8; ++ks) A[ks] = *(const bf16x8*)&p[ks * 64];
  };

  const f32x16 z16 = {0.f, 0.f, 0.f, 0.f, 0.f, 0.f, 0.f, 0.f,
                      0.f, 0.f, 0.f, 0.f, 0.f, 0.f, 0.f, 0.f};

  int hl = 2;
  int vbase = 2047 - 4 * lh;  // kr = vbase - row; m_local = tile*32+row+4*lh

  auto step = [&](bf16x8* A) {
    // all 16 MFMAs consume A before the refill below (ring-reuse hazard)
    f32x16 c0 = __builtin_amdgcn_mfma_f32_32x32x16_bf16(A[0], bfrag[0][0], z16,
                                                        0, 0, 0);
    f32x16 c1 = __builtin_amdgcn_mfma_f32_32x32x16_bf16(A[0], bfrag[1][0], z16,
                                                        0, 0, 0);
#pragma unroll
    for (int ks = 1; ks < 8; ++ks) {
      c0 = __builtin_amdgcn_mfma_f32_32x32x16_bf16(A[ks], bfrag[0][ks], c0,
                                                   0, 0, 0);
      c1 = __builtin_amdgcn_mfma_f32_32x32x16_bf16(A[ks], bfrag[1][ks], c1,
                                                   0, 0, 0);
    }
    if (hl < 32) loadA(A, hl);  // refill for use 2 steps later
    ++hl;
#pragma unroll
    for (int rg = 0; rg < 16; ++rg) {
      const unsigned kr = (unsigned)(vbase - ((rg & 3) + 8 * (rg >> 2)));
      float k = __uint_as_float((__float_as_uint(c0[rg]) & 0xFFFFF800u) | kr);
      tch[0][3] = fmed3(k, tch[0][2], tch[0][3]);
      tch[0][2] = fmed3(k, tch[0][1], tch[0][2]);
      tch[0][1] = fmed3(k, tch[0][0], tch[0][1]);
      tch[0][0] = fmaxf(tch[0][0], k);
      k = __uint_as_float((__float_as_uint(c1[rg]) & 0xFFFFF800u) | kr);
      tch[1][3] = fmed3(k, tch[1][2], tch[1][3]);
      tch[1][2] = fmed3(k, tch[1][1], tch[1][2]);
      tch[1][1] = fmed3(k, tch[1][0], tch[1][1]);
      tch[1][0] = fmaxf(tch[1][0], k);
    }
    vbase -= 32;
  };

  loadA(A0, 0);
  loadA(A1, 1);
  for (int g = 0; g < 16; ++g) { step(A0); step(A1); }  // tiles 0..31

  // ---- merge across lane-halves (rows complementary), snapshot-first ----
#pragma unroll
  for (int c = 0; c < 2; ++c) {
    float k4[4];
#pragma unroll
    for (int e = 0; e < 4; ++e) k4[e] = __shfl_xor(tch[c][e], 32, 64);
#pragma unroll
    for (int e = 0; e < 4; ++e) {
      const float k = k4[e];
      tch[c][3] = fmed3(k, tch[c][2], tch[c][3]);
      tch[c][2] = fmed3(k, tch[c][1], tch[c][2]);
      tch[c][1] = fmed3(k, tch[c][0], tch[c][1]);
      tch[c][0] = fmaxf(tch[c][0], k);
    }
  }

  // ---- 32 candidates per q-row (8 eighths x 4), 64 rows ----
  __shared__ float ck[64][33];
  __shared__ int top8[64][8];
  __shared__ double pd[64][8];
  __shared__ int pi[64][8];

  if (lane < 32) {
#pragma unroll
    for (int c = 0; c < 2; ++c)
#pragma unroll
      for (int e = 0; e < 4; ++e) ck[c * 32 + l31][w * 4 + e] = tch[c][e];
  }
  __syncthreads();

  // ---- rank-select top-8 of 32 packed keys per row (ranks unique) ----
  for (int p = tid; p < 2048; p += 512) {
    const int q = p >> 5;
    const int j = p & 31;
    const float k = ck[q][j];
    int rank = 0;
#pragma unroll 8
    for (int i = 0; i < 32; ++i) {
      const float o = ck[q][i];
      rank += (o > k) || (o == k && i < j);
    }
    if (rank < 8) {
      const unsigned bits = __float_as_uint(k);
      top8[q][rank] = (j >> 2) * 1024 + 2047 - (int)(bits & 0x7FFu);
    }
  }
  __syncthreads();

  // ---- fp64 refine: one candidate per thread (64 rows x 8) ----
  {
    const int q = tid >> 3;
    const int slot = tid & 7;
    const int m = top8[q][slot];
    const float* qrow = qry + ((size_t)b * NQ + qbase + q) * KD;
    const float* irow = img + ((size_t)b * NM + m) * KD;
    double s0 = 0.0, s1 = 0.0, s2 = 0.0, s3 = 0.0;
#pragma unroll
    for (int k = 0; k < KD; k += 4) {
      const float4 xv = *(const float4*)(qrow + k);
      const float4 yv = *(const float4*)(irow + k);
      s0 = fma((double)xv.x, (double)yv.x, s0);
      s1 = fma((double)xv.y, (double)yv.y, s1);
      s2 = fma((double)xv.z, (double)yv.z, s2);
      s3 = fma((double)xv.w, (double)yv.w, s3);
    }
    pd[q][slot] = (s0 + s1) + (s2 + s3);
    pi[q][slot] = m;
  }
  __syncthreads();

  // ---- exact top-4 of 8 refined, (value desc, index asc) ----
  if (tid < 64) {
    const int q = tid;
    double fv[4];
    int fi[4];
#pragma unroll
    for (int e = 0; e < 4; ++e) { fv[e] = -DBL_MAX; fi[e] = 0x7fffffff; }
    for (int sl = 0; sl < 8; ++sl) {
      const double v = pd[q][sl];
      const int m = pi[q][sl];
      const bool b0 = BETTER64(v, m, fv[0], fi[0]);
      const bool b1 = BETTER64(v, m, fv[1], fi[1]);
      const bool b2 = BETTER64(v, m, fv[2], fi[2]);
      const bool b3 = BETTER64(v, m, fv[3], fi[3]);
      fv[3] = b2 ? fv[2] : (b3 ? v : fv[3]);
      fi[3] = b2 ? fi[2] : (b3 ? m : fi[3]);
      fv[2] = b1 ? fv[1] : (b2 ? v : fv[2]);
      fi[2] = b1 ? fi[1] : (b2 ? m : fi[2]);
      fv[1] = b0 ? fv[0] : (b1 ? v : fv[1]);
      fi[1] = b0 ? fi[0] : (b1 ? m : fi[1]);
      fv[0] = b0 ? v : fv[0];
      fi[0] = b0 ? m : fi[0];
    }
    int4 o;
    o.x = fi[0]; o.y = fi[1]; o.z = fi[2]; o.w = fi[3];
    *(int4*)(out + ((size_t)b * NQ + qbase + q) * 4) = o;
  }
}

// ---------------- Fallback: fp32 LDS-tiled kernel (ws too small) ----------------
#define QT 64
#define MT 128
#define KC 64
#define NTHREADS 512

__global__ __launch_bounds__(NTHREADS) void wr_main(const float* __restrict__ qry,
                                                    const float* __restrict__ img,
                                                    int* __restrict__ out) {
  __shared__ __align__(16) float A_lds[KD * QT];
  __shared__ __align__(16) float B_lds[KC * MT];

  const int t = (int)threadIdx.x;
  const int b = (int)blockIdx.x >> 6;
  const int qbase = ((int)blockIdx.x & 63) * QT;

  const float* qp = qry + ((size_t)b * NQ + qbase) * KD;
  const float* ip = img + (size_t)b * NM * KD;

  {
    const int r = t >> 3;
    const int kc = t & 7;
    const float* src = qp + (size_t)r * KD;
#pragma unroll
    for (int i = 0; i < 4; ++i) {
      const int k0 = kc * 4 + i * 32;
      const float4 v = *(const float4*)(src + k0);
      A_lds[(k0 + 0) * QT + r] = v.x;
      A_lds[(k0 + 1) * QT + r] = v.y;
      A_lds[(k0 + 2) * QT + r] = v.z;
      A_lds[(k0 + 3) * QT + r] = v.w;
    }
  }

  const int qi = t >> 5;
  const int mi = t & 31;

  float tv[4][4];
  int ti[4][4];
#pragma unroll
  for (int j = 0; j < 4; ++j)
#pragma unroll
    for (int s = 0; s < 4; ++s) { tv[j][s] = -FLT_MAX; ti[j][s] = 0x7fffffff; }

  for (int tile = 0; tile < NM / MT; ++tile) {
    const int mbase = tile * MT;
    float acc[4][4];
#pragma unroll
    for (int j = 0; j < 4; ++j)
#pragma unroll
      for (int s = 0; s < 4; ++s) acc[j][s] = 0.0f;

    for (int kb = 0; kb < KD; kb += KC) {
      __syncthreads();
      {
        const int r = t >> 2;
        const int kc = t & 3;
        const float* src = ip + (size_t)(mbase + r) * KD + kb;
#pragma unroll
        for (int i = 0; i < 4; ++i) {
          const int k0 = kc * 4 + i * 16;
          const float4 v = *(const float4*)(src + k0);
          B_lds[(k0 + 0) * MT + r] = v.x;
          B_lds[(k0 + 1) * MT + r] = v.y;
          B_lds[(k0 + 2) * MT + r] = v.z;
          B_lds[(k0 + 3) * MT + r] = v.w;
        }
      }
      __syncthreads();

#pragma unroll 8
      for (int k = 0; k < KC; ++k) {
        const float4 av = *(const float4*)&A_lds[(kb + k) * QT + qi * 4];
        const float4 bv = *(const float4*)&B_lds[k * MT + mi * 4];
        acc[0][0] = fmaf(av.x, bv.x, acc[0][0]);
        acc[0][1] = fmaf(av.x, bv.y, acc[0][1]);
        acc[0][2] = fmaf(av.x, bv.z, acc[0][2]);
        acc[0][3] = fmaf(av.x, bv.w, acc[0][3]);
        acc[1][0] = fmaf(av.y, bv.x, acc[1][0]);
        acc[1][1] = fmaf(av.y, bv.y, acc[1][1]);
        acc[1][2] = fmaf(av.y, bv.z, acc[1][2]);
        acc[1][3] = fmaf(av.y, bv.w, acc[1][3]);
        acc[2][0] = fmaf(av.z, bv.x, acc[2][0]);
        acc[2][1] = fmaf(av.z, bv.y, acc[2][1]);
        acc[2][2] = fmaf(av.z, bv.z, acc[2][2]);
        acc[2][3] = fmaf(av.z, bv.w, acc[2][3]);
        acc[3][0] = fmaf(av.w, bv.x, acc[3][0]);
        acc[3][1] = fmaf(av.w, bv.y, acc[3][1]);
        acc[3][2] = fmaf(av.w, bv.z, acc[3][2]);
        acc[3][3] = fmaf(av.w, bv.w, acc[3][3]);
      }
    }

#pragma unroll
    for (int j = 0; j < 4; ++j) {
#pragma unroll
      for (int s = 0; s < 4; ++s) {
        const float v = acc[j][s];
        const int m = mbase + mi * 4 + s;
        const bool b0 = v > tv[j][0];
        const bool b1 = v > tv[j][1];
        const bool b2 = v > tv[j][2];
        const bool b3 = v > tv[j][3];
        tv[j][3] = b2 ? tv[j][2] : (b3 ? v : tv[j][3]);
        ti[j][3] = b2 ? ti[j][2] : (b3 ? m : ti[j][3]);
        tv[j][2] = b1 ? tv[j][1] : (b2 ? v : tv[j][2]);
        ti[j][2] = b1 ? ti[j][1] : (b2 ? m : ti[j][2]);
        tv[j][1] = b0 ? tv[j][0] : (b1 ? v : tv[j][1]);
        ti[j][1] = b0 ? ti[j][0] : (b1 ? m : ti[j][1]);
        tv[j][0] = b0 ? v : tv[j][0];
        ti[j][0] = b0 ? m : ti[j][0];
      }
    }
  }

  __syncthreads();
  int* idx_lds = (int*)B_lds;
#pragma unroll
  for (int j = 0; j < 4; ++j)
#pragma unroll
    for (int s = 0; s < 4; ++s)
      idx_lds[(qi * 4 + j) * 128 + mi * 4 + s] = ti[j][s];
  __syncthreads();

  double* pv = (double*)A_lds;
  int* piL = (int*)(A_lds + 4096);
  {
    const int r = t >> 3;
    const int slot = t & 7;
    const float* qrow = qp + (size_t)r * KD;
    double bv[4];
    int bi[4];
#pragma unroll
    for (int e = 0; e < 4; ++e) { bv[e] = -DBL_MAX; bi[e] = 0x7fffffff; }

    for (int c = 0; c < 16; ++c) {
      const int m = idx_lds[r * 128 + slot * 16 + c];
      const float* irow = ip + (size_t)m * KD;
      double s0 = 0.0, s1 = 0.0, s2 = 0.0, s3 = 0.0;
#pragma unroll
      for (int k = 0; k < KD; k += 4) {
        const float4 xv = *(const float4*)(qrow + k);
        const float4 yv = *(const float4*)(irow + k);
        s0 = fma((double)xv.x, (double)yv.x, s0);
        s1 = fma((double)xv.y, (double)yv.y, s1);
        s2 = fma((double)xv.z, (double)yv.z, s2);
        s3 = fma((double)xv.w, (double)yv.w, s3);
      }
      const double v = (s0 + s1) + (s2 + s3);
      const bool b0 = BETTER64(v, m, bv[0], bi[0]);
      const bool b1 = BETTER64(v, m, bv[1], bi[1]);
      const bool b2 = BETTER64(v, m, bv[2], bi[2]);
      const bool b3 = BETTER64(v, m, bv[3], bi[3]);
      bv[3] = b2 ? bv[2] : (b3 ? v : bv[3]);
      bi[3] = b2 ? bi[2] : (b3 ? m : bi[3]);
      bv[2] = b1 ? bv[1] : (b2 ? v : bv[2]);
      bi[2] = b1 ? bi[1] : (b2 ? m : bi[2]);
      bv[1] = b0 ? bv[0] : (b1 ? v : bv[1]);
      bi[1] = b0 ? bi[0] : (b1 ? m : bi[1]);
      bv[0] = b0 ? v : bv[0];
      bi[0] = b0 ? m : bi[0];
    }
#pragma unroll
    for (int e = 0; e < 4; ++e) {
      pv[t * 4 + e] = bv[e];
      piL[t * 4 + e] = bi[e];
    }
  }
  __syncthreads();

  if (t < QT) {
    double fv[4];
    int fi[4];
#pragma unroll
    for (int e = 0; e < 4; ++e) { fv[e] = -DBL_MAX; fi[e] = 0x7fffffff; }
    for (int sl = 0; sl < 8; ++sl) {
#pragma unroll
      for (int e = 0; e < 4; ++e) {
        const double v = pv[(t * 8 + sl) * 4 + e];
        const int m = piL[(t * 8 + sl) * 4 + e];
        const bool b0 = BETTER64(v, m, fv[0], fi[0]);
        const bool b1 = BETTER64(v, m, fv[1], fi[1]);
        const bool b2 = BETTER64(v, m, fv[2], fi[2]);
        const bool b3 = BETTER64(v, m, fv[3], fi[3]);
        fv[3] = b2 ? fv[2] : (b3 ? v : fv[3]);
        fi[3] = b2 ? fi[2] : (b3 ? m : fi[3]);
        fv[2] = b1 ? fv[1] : (b2 ? v : fv[2]);
        fi[2] = b1 ? fi[1] : (b2 ? m : fi[2]);
        fv[1] = b0 ? fv[0] : (b1 ? v : fv[1]);
        fi[1] = b0 ? fi[0] : (b1 ? m : fi[1]);
        fv[0] = b0 ? v : fv[0];
        fi[0] = b0 ? m : fi[0];
      }
    }
    int4 o;
    o.x = fi[0]; o.y = fi[1]; o.z = fi[2]; o.w = fi[3];
    *(int4*)(out + ((size_t)b * NQ + qbase + t) * 4) = o;
  }
}

extern "C" void kernel_launch(void* const* d_in, const int* in_sizes, int n_in,
                              void* d_out, int out_size, void* d_ws, size_t ws_size,
                              hipStream_t stream) {
  const float* qry = (const float*)d_in[0];  // (4, 4096, 128) fp32
  const float* img = (const float*)d_in[1];  // (4, 8192, 128) fp32
  int* out = (int*)d_out;                    // (4, 4096, 4) int32

  const size_t qbBytes = (size_t)NBATCH * NQ * KD * sizeof(ushort_t);  // 4 MB
  const size_t ibBytes = (size_t)NBATCH * NM * KD * sizeof(ushort_t);  // 8 MB

  if (ws_size >= qbBytes + ibBytes) {
    int4* qb = (int4*)d_ws;
    int4* ib = (int4*)((char*)d_ws + qbBytes);
    wr_cvt<<<3072, 256, 0, stream>>>(qry, img, qb, ib);
    wr_mfma<<<256, 512, 0, stream>>>(qry, img, qb, ib, out);
  } else {
    wr_main<<<NBATCH * (NQ / QT), NTHREADS, 0, stream>>>(qry, img, out);
  }
}